// Round 12
// baseline (418.192 us; speedup 1.0000x reference)
//
#include <hip/hip_runtime.h>
#include <hip/hip_cooperative_groups.h>
#include <math.h>

namespace cg = cooperative_groups;

#define DIM 64
#define NBLK_C 256       // cooperative build grid: 1 block/CU, guaranteed co-resident
#define NTHR 1024
#define CBSZ 1024        // rows per coarse bucket (R10-verified): write-amp ~1.2-1.4x + full occ
#define CBMAX 256        // CB = ceil(R/1024) = 245 <= 256

// PMC-verified lessons: R5/R8 global atomics & scattered 8B stores = line-granular HBM
// round-trips (atomics stay in LDS); R6 1024-thr layer blocks -> degree-variance tail;
// R9 grids < 256 blocks starve CUs; R3 fine buckets -> 3.3x write amplification.

typedef unsigned short ushort_t;
typedef unsigned int uint_t;
typedef unsigned char uchar_t;
typedef float v2f __attribute__((ext_vector_type(2)));

__device__ __forceinline__ ushort_t f2bf(float f) {
    uint_t u = __float_as_uint(f);
    return (ushort_t)((u + 0x7fffu + ((u >> 16) & 1u)) >> 16);
}

// ---- x4-vectorized edge sweeps (count/place use IDENTICAL quad mapping for offset consistency)

__device__ __forceinline__ void count_list(const int* __restrict__ rows, int EL, int base,
                                           int* h, size_t gtid, size_t GT) {
    size_t nq = ((size_t)EL + 3) >> 2;
    for (size_t q = gtid; q < nq; q += GT) {
        int e = (int)(q << 2);
        if (e + 4 <= EL) {
            int4 r4 = *(const int4*)(rows + e);
            atomicAdd(&h[(base + r4.x) >> 10], 1);
            atomicAdd(&h[(base + r4.y) >> 10], 1);
            atomicAdd(&h[(base + r4.z) >> 10], 1);
            atomicAdd(&h[(base + r4.w) >> 10], 1);
        } else {
            for (int j = e; j < EL; j++) atomicAdd(&h[(base + rows[j]) >> 10], 1);
        }
    }
}

__device__ __forceinline__ void place_edge(int v, int c, float r1, float r2,
                                           float w1, float b1, float w2, float b2,
                                           int* cur, uint2* __restrict__ barr) {
    float t1 = expf(expf(1.0f / (1.0f + expf(-(r1 * w1 + b1)))));
    float t2 = expf(expf(1.0f / (1.0f + expf(-(r2 * w2 + b2)))));
    uint_t packed = (uint_t)f2bf(t1) | ((uint_t)f2bf(t2) << 16);
    int pos = atomicAdd(&cur[v >> 10], 1);
    barr[pos] = make_uint2(((uint_t)(v & 1023) << 22) | (uint_t)c, packed);
}

__device__ __forceinline__ void place_list(const int* __restrict__ rows, const int* __restrict__ cols,
                                           const float* __restrict__ x1, const float* __restrict__ x2,
                                           int EL, int base, float w1, float b1, float w2, float b2,
                                           int* cur, uint2* __restrict__ barr,
                                           size_t gtid, size_t GT) {
    size_t nq = ((size_t)EL + 3) >> 2;
    for (size_t q = gtid; q < nq; q += GT) {
        int e = (int)(q << 2);
        if (e + 4 <= EL) {
            int4 r4 = *(const int4*)(rows + e);
            int4 c4 = *(const int4*)(cols + e);
            float4 a4 = *(const float4*)(x1 + e);
            float4 b4 = *(const float4*)(x2 + e);
            place_edge(base + r4.x, c4.x, a4.x, b4.x, w1, b1, w2, b2, cur, barr);
            place_edge(base + r4.y, c4.y, a4.y, b4.y, w1, b1, w2, b2, cur, barr);
            place_edge(base + r4.z, c4.z, a4.z, b4.z, w1, b1, w2, b2, cur, barr);
            place_edge(base + r4.w, c4.w, a4.w, b4.w, w1, b1, w2, b2, cur, barr);
        } else {
            for (int j = e; j < EL; j++)
                place_edge(base + rows[j], cols[j], x1[j], x2[j], w1, b1, w2, b2, cur, barr);
        }
    }
}

// ---------------- R12: fused CSR build — one cooperative kernel, 4 phases --------------------
// P1 cvt+count | P2 blkscan (block b = bucket b) | P3 cb_prefix + place | P4 finalize.
// LDS (cs) persists across grid.sync() so P4 reuses P3's prefix for free.

__global__ __launch_bounds__(NTHR, 4)
void build_kernel(const float* __restrict__ u0f, const float* __restrict__ i0f,
                  uchar_t* __restrict__ ub, uchar_t* __restrict__ ib,
                  size_t n8u, size_t n8t,
                  const int* __restrict__ sn_row, const int* __restrict__ sn_col,
                  const int* __restrict__ ci_row, const int* __restrict__ ci_col,
                  const int* __restrict__ ic_row, const int* __restrict__ ic_col,
                  const float* __restrict__ snii1, const float* __restrict__ snii2,
                  const float* __restrict__ ciii1, const float* __restrict__ ciii2,
                  const float* __restrict__ icii1, const float* __restrict__ icii2,
                  const float* __restrict__ lw, const float* __restrict__ lb,
                  int* __restrict__ cnt, int* __restrict__ blkoff, int* __restrict__ total,
                  int* __restrict__ ptr, uint2* __restrict__ barr, uint2* __restrict__ rec,
                  int Es, int Eui, int Eiu, int U, int R, int CB) {
    cg::grid_group grid = cg::this_grid();
    __shared__ int h[CBMAX];
    __shared__ int ws2[4];
    __shared__ int cs[CBMAX + 1];
    __shared__ int wsx[4];
    __shared__ int cur[CBMAX];
    __shared__ int hist[CBSZ];
    __shared__ int cur2[CBSZ];
    __shared__ int wss[NTHR / 64];

    int b = blockIdx.x, tid = threadIdx.x;
    size_t gtid = (size_t)b * NTHR + tid;
    const size_t GT = (size_t)NBLK_C * NTHR;

    // ---- P1: fp8 cvt (emb ~N(0,0.01^2) x256, e4m3 range; absmax 0.0 verified) + count ----
    for (size_t i = gtid; i < n8t; i += GT) {
        const float4* src; uchar_t* dst; size_t di;
        if (i < n8u) { src = (const float4*)u0f; dst = ub; di = i; }
        else         { src = (const float4*)i0f; dst = ib; di = i - n8u; }
        float4 a = src[2 * di], c = src[2 * di + 1];
        int lo = 0, hi = 0;
        lo = __builtin_amdgcn_cvt_pk_fp8_f32(a.x * 256.0f, a.y * 256.0f, lo, false);
        lo = __builtin_amdgcn_cvt_pk_fp8_f32(a.z * 256.0f, a.w * 256.0f, lo, true);
        hi = __builtin_amdgcn_cvt_pk_fp8_f32(c.x * 256.0f, c.y * 256.0f, hi, false);
        hi = __builtin_amdgcn_cvt_pk_fp8_f32(c.z * 256.0f, c.w * 256.0f, hi, true);
        ((uint2*)dst)[di] = make_uint2((uint_t)lo, (uint_t)hi);
    }
    if (tid < CBMAX) h[tid] = 0;
    __syncthreads();
    count_list(sn_row, Es, 0, h, gtid, GT);
    count_list(ci_row, Eui, U, h, gtid, GT);
    count_list(ic_row, Eiu, 2 * U, h, gtid, GT);
    __syncthreads();
    if (tid < CB) cnt[(size_t)b * CB + tid] = h[tid];
    grid.sync();

    // ---- P2: per-bucket exclusive scan over the 256 blocks (block b = bucket b) ----
    if (b < CB) {
        int lane = tid & 63, wv = tid >> 6;
        int v = 0, inc = 0;
        if (tid < NBLK_C) {
            v = cnt[(size_t)tid * CB + b];
            inc = v;
            #pragma unroll
            for (int off = 1; off < 64; off <<= 1) {
                int x = __shfl_up(inc, off, 64);
                if (lane >= off) inc += x;
            }
            if (lane == 63) ws2[wv] = inc;
        }
        __syncthreads();
        if (tid < NBLK_C) {
            int woff = 0;
            for (int j = 0; j < wv; j++) woff += ws2[j];
            blkoff[(size_t)tid * CB + b] = inc - v + woff;
            if (tid == NBLK_C - 1) total[b] = inc + woff;
        }
    }
    grid.sync();

    // ---- P3: inline CB-prefix (persists in cs[] for P4) + place ----
    {
        int lane = tid & 63, wv = tid >> 6;
        int v = 0, inc = 0;
        if (tid < 256) {
            v = (tid < CB) ? total[tid] : 0;
            inc = v;
            #pragma unroll
            for (int off = 1; off < 64; off <<= 1) {
                int x = __shfl_up(inc, off, 64);
                if (lane >= off) inc += x;
            }
            if (lane == 63) wsx[wv] = inc;
        }
        __syncthreads();
        if (tid < 256) {
            int woff = 0;
            for (int j = 0; j < wv; j++) woff += wsx[j];
            if (tid < CB) cs[tid] = inc - v + woff;
            if (tid == CB - 1) cs[CB] = inc + woff;   // = E
        }
        __syncthreads();
    }
    if (tid < CB) cur[tid] = cs[tid] + blkoff[(size_t)b * CB + tid];
    __syncthreads();
    place_list(sn_row, sn_col, snii1, snii2, Es, 0,      lw[0], lb[0], lw[1], lb[1], cur, barr, gtid, GT);
    place_list(ci_row, ci_col, ciii1, ciii2, Eui, U,     lw[2], lb[2], lw[3], lb[3], cur, barr, gtid, GT);
    place_list(ic_row, ic_col, icii1, icii2, Eiu, 2 * U, lw[4], lb[4], lw[5], lb[5], cur, barr, gtid, GT);
    grid.sync();

    // ---- P4: finalize bucket b (1024-row histo + scan + single-writer scatter) ----
    if (b < CB) {
        int s0 = cs[b], s1 = cs[b + 1];
        hist[tid] = 0;
        __syncthreads();
        for (int e = s0 + tid; e < s1; e += NTHR)
            atomicAdd(&hist[barr[e].x >> 22], 1);
        __syncthreads();
        int v = hist[tid];
        int lane = tid & 63, wv = tid >> 6;
        int inc = v;
        #pragma unroll
        for (int off = 1; off < 64; off <<= 1) {
            int x = __shfl_up(inc, off, 64);
            if (lane >= off) inc += x;
        }
        if (lane == 63) wss[wv] = inc;
        __syncthreads();
        int woff = 0;
        for (int j = 0; j < wv; j++) woff += wss[j];
        int p0 = s0 + inc - v + woff;                 // CSR start for row b*1024+tid
        int r = b * CBSZ + tid;
        if (r < R) ptr[r] = p0;
        cur2[tid] = p0;
        if (b == CB - 1 && tid == 0) ptr[R] = cs[CB];
        __syncthreads();
        for (int e = s0 + tid; e < s1; e += NTHR) {
            uint2 q = barr[e];
            int rin = (int)(q.x >> 22);
            int pos = atomicAdd(&cur2[rin], 1);
            rec[pos] = make_uint2(q.x & 0x3FFFFFu, q.y);
        }
    }
}

// ---------------- layer kernels ----------------

__device__ __forceinline__ float att_scalar(float dot, float b1, float w2, float b2, float addc) {
    float h = tanhf(dot + b1);
    float z = h * w2 + b2;
    float lr = z > 0.0f ? z : 0.2f * z;   // leaky_relu alpha=0.2
    return expf(lr) + addc;
}

// packed fp8 -> float2 FMA: 4 cvt + 4 packed FMAs per 8 dims (v_pk_fma_f32)
__device__ __forceinline__ void fp8_fma8v(v2f acc[4], uint2 v, float a) {
    v2f av = {a, a};
    acc[0] += av * __builtin_amdgcn_cvt_pk_f32_fp8((int)v.x, false);
    acc[1] += av * __builtin_amdgcn_cvt_pk_f32_fp8((int)v.x, true);
    acc[2] += av * __builtin_amdgcn_cvt_pk_f32_fp8((int)v.y, false);
    acc[3] += av * __builtin_amdgcn_cvt_pk_f32_fp8((int)v.y, true);
}

__device__ __forceinline__ float dot8_lanes(float d) {
    #pragma unroll
    for (int off = 1; off < 8; off <<= 1) d += __shfl_xor(d, off, 64);
    return d;
}

// BRANCH-FREE batched CSR walk (R14). 8 lanes load 8 different records (coalesced),
// prefetch next batch via clamped load + cndmask. Padded records are (0,0): cx=0 is a
// valid row-0 gather and a=0 makes the FMA a no-op -> no divergent branches, 8
// independent gathers clustered per batch.
__device__ __forceinline__ void agg_row8(const uint2* __restrict__ rec, const uchar_t* __restrict__ tab,
                                         int e0, int e1, int l8, int lanebase,
                                         v2f acc[4], float& s) {
    if (e0 >= e1) return;
    int last = e1 - 1;
    int idx0 = e0 + l8;
    uint2 t0 = rec[min(idx0, last)];
    uint2 q;
    q.x = (idx0 <= last) ? t0.x : 0u;
    q.y = (idx0 <= last) ? t0.y : 0u;
    for (int base = e0; base < e1; base += 8) {
        int nidx = base + 8 + l8;
        uint2 tn = rec[min(nidx, last)];          // unconditional clamped prefetch
        uint2 qn;
        qn.x = (nidx <= last) ? tn.x : 0u;
        qn.y = (nidx <= last) ? tn.y : 0u;
        s += __uint_as_float(q.y << 16);          // per-lane partial of bf16 t1 (0 if padded)
        #pragma unroll
        for (int j = 0; j < 8; j++) {
            uint_t cx = __shfl(q.x, lanebase + j, 64);
            uint_t wy = __shfl(q.y, lanebase + j, 64);
            float a = __uint_as_float(wy << 16);
            uint2 v = ((const uint2*)(tab + (size_t)cx * DIM))[l8];
            fp8_fma8v(acc, v, a);
        }
        q = qn;
    }
}

// one row per 8-lane group; 256-thr blocks (R6 lesson: 1024-thr blocks -> 41% occupancy).
__global__ void layer1_kernel(const uchar_t* __restrict__ ub8, const uchar_t* __restrict__ ib8,
                              const float* __restrict__ u0, const float* __restrict__ i0,
                              const int* __restrict__ ptr, const uint2* __restrict__ rec,
                              const float* __restrict__ W1, const float* __restrict__ b1v,
                              const float* __restrict__ w2v, const float* __restrict__ b2v,
                              float* __restrict__ u1, float* __restrict__ i1, int U, int I) {
    int gid = blockIdx.x * (blockDim.x >> 3) + (threadIdx.x >> 3);
    int lane = threadIdx.x & 63;
    int l8 = lane & 7;
    int lanebase = lane & 56;
    if (gid >= U + I) return;
    bool is_user = gid < U;
    int r = is_user ? gid : gid - U;

    v2f A[4]  = {{0.f, 0.f}, {0.f, 0.f}, {0.f, 0.f}, {0.f, 0.f}};
    v2f Bv[4] = {{0.f, 0.f}, {0.f, 0.f}, {0.f, 0.f}, {0.f, 0.f}};
    float s_a = 0.f, s_b = 0.f;

    if (is_user) {
        agg_row8(rec, ib8, ptr[U + r], ptr[U + r + 1], l8, lanebase, A, s_a);   // u_from_i (ci)
        agg_row8(rec, ub8, ptr[r], ptr[r + 1], l8, lanebase, Bv, s_b);          // u_from_u (sn)
    } else {
        agg_row8(rec, ub8, ptr[2 * U + r], ptr[2 * U + r + 1], l8, lanebase, A, s_a);  // i_from_u (ic)
    }
    s_a = dot8_lanes(s_a);
    s_b = dot8_lanes(s_b);

    float ka = (1.0f / (s_a + 1e-12f)) * 0.00390625f;   // softmax denom * fp8 scale
    float kb = (1.0f / (s_b + 1e-12f)) * 0.00390625f;
    float ac[8], bc[8];
    #pragma unroll
    for (int j = 0; j < 4; j++) {
        ac[2 * j] = A[j][0] * ka;  ac[2 * j + 1] = A[j][1] * ka;
        bc[2 * j] = Bv[j][0] * kb; bc[2 * j + 1] = Bv[j][1] * kb;
    }

    const float* selfp = (is_user ? u0 : i0) + (size_t)r * DIM + 8 * l8;
    float4 s0 = *(const float4*)selfp;
    float4 s1 = *(const float4*)(selfp + 4);
    float sf[8] = {s0.x, s0.y, s0.z, s0.w, s1.x, s1.y, s1.z, s1.w};
    int k = is_user ? 0 : 4;
    const float* Wa = W1 + k * 2 * DIM;
    const float* Wb = Wa + 2 * DIM;
    float d1 = 0.f, d2 = 0.f;
    #pragma unroll
    for (int j = 0; j < 8; j++) {
        float wa0 = Wa[8 * l8 + j], wa1 = Wa[DIM + 8 * l8 + j];
        float wb0 = Wb[8 * l8 + j], wb1 = Wb[DIM + 8 * l8 + j];
        if (is_user) {
            d1 += sf[j] * wa0 + ac[j] * wa1;
            d2 += sf[j] * wb0 + bc[j] * wb1;
        } else {
            d1 += sf[j] * (wa0 + wa1);                 // concat([it, it])
            d2 += sf[j] * wb0 + ac[j] * wb1;
        }
    }
    d1 = dot8_lanes(d1);
    d2 = dot8_lanes(d2);

    float out8[8];
    float* op;
    if (is_user) {
        float a_int = att_scalar(d1, b1v[0], w2v[0], b2v[0], 0.7f);
        float a_soc = att_scalar(d2, b1v[1], w2v[1], b2v[1], 0.3f);
        float sg = a_int + a_soc;
        float wi = a_int / sg, ws = a_soc / sg;
        #pragma unroll
        for (int j = 0; j < 8; j++)
            out8[j] = 0.5f * sf[j] + 0.5f * (wi * ac[j] + ws * bc[j]);
        op = u1 + (size_t)r * DIM + 8 * l8;
    } else {
        float a_self = att_scalar(d1, b1v[4], w2v[4], b2v[4], 1.0f);
        float a_cust = att_scalar(d2, b1v[5], w2v[5], b2v[5], 1.0f);
        float sg = a_self + a_cust;
        float wi = a_self / sg, ws = a_cust / sg;
        #pragma unroll
        for (int j = 0; j < 8; j++)
            out8[j] = wi * sf[j] + ws * ac[j];
        op = i1 + (size_t)r * DIM + 8 * l8;
    }
    *(float4*)op = make_float4(out8[0], out8[1], out8[2], out8[3]);
    *(float4*)(op + 4) = make_float4(out8[4], out8[5], out8[6], out8[7]);
}

// ---------------- fused layer2+final — one wave per sample; u2/i2 never hit global ----------

__global__ void l2f_kernel(const float* __restrict__ u0, const float* __restrict__ i0,
                           const float* __restrict__ u1, const float* __restrict__ i1,
                           const int* __restrict__ ptr, const uint2* __restrict__ rec,
                           const float* __restrict__ W1, const float* __restrict__ b1v,
                           const float* __restrict__ w2v, const float* __restrict__ b2v,
                           const int* __restrict__ uidx, const int* __restrict__ iidx,
                           float* __restrict__ out, int U, int B) {
    int wid = blockIdx.x * (blockDim.x >> 6) + (threadIdx.x >> 6);
    int lane = threadIdx.x & 63;
    if (wid >= B) return;
    int g = lane >> 3, l8 = lane & 7;
    int ru = uidx[wid], ri = iidx[wid];

    // ---- user phase: u2 row of ru ----
    float aa[8] = {0, 0, 0, 0, 0, 0, 0, 0};
    float ab[8] = {0, 0, 0, 0, 0, 0, 0, 0};
    float s_a = 0.f, s_b = 0.f;
    int e0 = ptr[U + ru], e1 = ptr[U + ru + 1];
    for (int e = e0 + g; e < e1; e += 8) {
        uint2 q = rec[e];
        float a = __uint_as_float(q.y & 0xffff0000u);  // bf16 t2
        s_a += a;
        const float4* rp = (const float4*)(i1 + (size_t)q.x * DIM);
        float4 v0 = rp[2 * l8], v1 = rp[2 * l8 + 1];
        aa[0] = fmaf(a, v0.x, aa[0]); aa[1] = fmaf(a, v0.y, aa[1]);
        aa[2] = fmaf(a, v0.z, aa[2]); aa[3] = fmaf(a, v0.w, aa[3]);
        aa[4] = fmaf(a, v1.x, aa[4]); aa[5] = fmaf(a, v1.y, aa[5]);
        aa[6] = fmaf(a, v1.z, aa[6]); aa[7] = fmaf(a, v1.w, aa[7]);
    }
    e0 = ptr[ru]; e1 = ptr[ru + 1];
    for (int e = e0 + g; e < e1; e += 8) {
        uint2 q = rec[e];
        float a = __uint_as_float(q.y & 0xffff0000u);
        s_b += a;
        const float4* rp = (const float4*)(u1 + (size_t)q.x * DIM);
        float4 v0 = rp[2 * l8], v1 = rp[2 * l8 + 1];
        ab[0] = fmaf(a, v0.x, ab[0]); ab[1] = fmaf(a, v0.y, ab[1]);
        ab[2] = fmaf(a, v0.z, ab[2]); ab[3] = fmaf(a, v0.w, ab[3]);
        ab[4] = fmaf(a, v1.x, ab[4]); ab[5] = fmaf(a, v1.y, ab[5]);
        ab[6] = fmaf(a, v1.z, ab[6]); ab[7] = fmaf(a, v1.w, ab[7]);
    }
    #pragma unroll
    for (int off = 8; off < 64; off <<= 1) {
        s_a += __shfl_xor(s_a, off, 64);
        s_b += __shfl_xor(s_b, off, 64);
        #pragma unroll
        for (int j = 0; j < 8; j++) {
            aa[j] += __shfl_xor(aa[j], off, 64);
            ab[j] += __shfl_xor(ab[j], off, 64);
        }
    }
    float ka = 1.0f / (s_a + 1e-12f);
    float kb = 1.0f / (s_b + 1e-12f);
    #pragma unroll
    for (int j = 0; j < 8; j++) { aa[j] *= ka; ab[j] *= kb; }

    const float* sup = u1 + (size_t)ru * DIM + 8 * l8;
    float4 su0 = *(const float4*)sup;
    float4 su1 = *(const float4*)(sup + 4);
    float sfu[8] = {su0.x, su0.y, su0.z, su0.w, su1.x, su1.y, su1.z, su1.w};
    {
        const float* Wa = W1 + 2 * 2 * DIM;            // k=2
        const float* Wb = Wa + 2 * DIM;
        float d1 = 0.f, d2 = 0.f;
        #pragma unroll
        for (int j = 0; j < 8; j++) {
            d1 += sfu[j] * Wa[8 * l8 + j] + aa[j] * Wa[DIM + 8 * l8 + j];
            d2 += sfu[j] * Wb[8 * l8 + j] + ab[j] * Wb[DIM + 8 * l8 + j];
        }
        d1 = dot8_lanes(d1);
        d2 = dot8_lanes(d2);
        float a_int = att_scalar(d1, b1v[2], w2v[2], b2v[2], 0.7f);
        float a_soc = att_scalar(d2, b1v[3], w2v[3], b2v[3], 0.3f);
        float sg = a_int + a_soc;
        float wi = a_int / sg, ws = a_soc / sg;
        #pragma unroll
        for (int j = 0; j < 8; j++)
            aa[j] = 0.5f * sfu[j] + 0.5f * (wi * aa[j] + ws * ab[j]);   // aa := u2 dims
    }

    // ---- item phase: i2 row of ri ----
    float ac[8] = {0, 0, 0, 0, 0, 0, 0, 0};
    float s_c = 0.f;
    e0 = ptr[2 * U + ri]; e1 = ptr[2 * U + ri + 1];
    for (int e = e0 + g; e < e1; e += 8) {
        uint2 q = rec[e];
        float a = __uint_as_float(q.y & 0xffff0000u);
        s_c += a;
        const float4* rp = (const float4*)(u1 + (size_t)q.x * DIM);
        float4 v0 = rp[2 * l8], v1 = rp[2 * l8 + 1];
        ac[0] = fmaf(a, v0.x, ac[0]); ac[1] = fmaf(a, v0.y, ac[1]);
        ac[2] = fmaf(a, v0.z, ac[2]); ac[3] = fmaf(a, v0.w, ac[3]);
        ac[4] = fmaf(a, v1.x, ac[4]); ac[5] = fmaf(a, v1.y, ac[5]);
        ac[6] = fmaf(a, v1.z, ac[6]); ac[7] = fmaf(a, v1.w, ac[7]);
    }
    #pragma unroll
    for (int off = 8; off < 64; off <<= 1) {
        s_c += __shfl_xor(s_c, off, 64);
        #pragma unroll
        for (int j = 0; j < 8; j++) ac[j] += __shfl_xor(ac[j], off, 64);
    }
    float kc = 1.0f / (s_c + 1e-12f);
    #pragma unroll
    for (int j = 0; j < 8; j++) ac[j] *= kc;

    const float* sip = i1 + (size_t)ri * DIM + 8 * l8;
    float4 si0 = *(const float4*)sip;
    float4 si1 = *(const float4*)(sip + 4);
    float sfi[8] = {si0.x, si0.y, si0.z, si0.w, si1.x, si1.y, si1.z, si1.w};
    {
        const float* Wa = W1 + 6 * 2 * DIM;            // k=6
        const float* Wb = Wa + 2 * DIM;
        float d1 = 0.f, d2 = 0.f;
        #pragma unroll
        for (int j = 0; j < 8; j++) {
            d1 += sfi[j] * (Wa[8 * l8 + j] + Wa[DIM + 8 * l8 + j]);   // concat([it, it])
            d2 += sfi[j] * Wb[8 * l8 + j] + ac[j] * Wb[DIM + 8 * l8 + j];
        }
        d1 = dot8_lanes(d1);
        d2 = dot8_lanes(d2);
        float a_self = att_scalar(d1, b1v[6], w2v[6], b2v[6], 1.0f);
        float a_cust = att_scalar(d2, b1v[7], w2v[7], b2v[7], 1.0f);
        float sg = a_self + a_cust;
        float wi = a_self / sg, ws = a_cust / sg;
        #pragma unroll
        for (int j = 0; j < 8; j++)
            ac[j] = wi * sfi[j] + ws * ac[j];           // ac := i2 dims
    }

    // ---- final: sigmoid(u0.i0 + u1.i1 + u2.i2) ----
    float p = 0.f;
    #pragma unroll
    for (int j = 0; j < 8; j++) p += aa[j] * ac[j];
    p = dot8_lanes(p);                                  // u2.i2 (same in all lanes)
    float qd = u0[(size_t)ru * DIM + lane] * i0[(size_t)ri * DIM + lane]
             + u1[(size_t)ru * DIM + lane] * i1[(size_t)ri * DIM + lane];
    #pragma unroll
    for (int off = 32; off > 0; off >>= 1) qd += __shfl_xor(qd, off, 64);
    if (lane == 0) out[wid] = 1.0f / (1.0f + expf(-(p + qd)));
}

// ---------------- launch ----------------

extern "C" void kernel_launch(void* const* d_in, const int* in_sizes, int n_in,
                              void* d_out, int out_size, void* d_ws, size_t ws_size,
                              hipStream_t stream) {
    const float* user_emb = (const float*)d_in[0];
    const float* item_emb = (const float*)d_in[1];
    const float* snii1 = (const float*)d_in[2];
    const float* snii2 = (const float*)d_in[3];
    const float* ciii1 = (const float*)d_in[4];
    const float* ciii2 = (const float*)d_in[5];
    const float* icii1 = (const float*)d_in[6];
    const float* icii2 = (const float*)d_in[7];
    const float* low_w = (const float*)d_in[8];
    const float* low_b = (const float*)d_in[9];
    const float* att1_W = (const float*)d_in[10];
    const float* att1_b = (const float*)d_in[11];
    const float* att2_w = (const float*)d_in[12];
    const float* att2_b = (const float*)d_in[13];
    const int* sn_row = (const int*)d_in[14];
    const int* sn_col = (const int*)d_in[15];
    const int* ci_row = (const int*)d_in[16];
    const int* ci_col = (const int*)d_in[17];
    const int* ic_row = (const int*)d_in[18];
    const int* ic_col = (const int*)d_in[19];
    const int* user_idx = (const int*)d_in[20];
    const int* item_idx = (const int*)d_in[21];
    float* out = (float*)d_out;

    const int Es  = in_sizes[2];
    const int Eui = in_sizes[4];
    const int Eiu = in_sizes[6];
    const int U = in_sizes[0] / DIM;
    const int I = in_sizes[1] / DIM;
    const int B = in_sizes[20];
    const int R = 2 * U + I;                // virtual rows: [0,U)=sn, [U,2U)=ci, [2U,2U+I)=ic
    const int CB = (R + CBSZ - 1) / CBSZ;   // 245 coarse buckets <= CBMAX
    const int E = Es + Eui + Eiu;
    (void)E;

    // ---- workspace carve (4-byte units, 16B-aligned) ----
    char* wsb = (char*)d_ws;
    size_t off = 0;
    auto alloc = [&](size_t n_units) {
        off = (off + 3) & ~(size_t)3;
        void* p = wsb + off * 4; off += n_units; return p;
    };

    int* cnt    = (int*)alloc((size_t)NBLK_C * CB);
    int* blkoff = (int*)alloc((size_t)NBLK_C * CB);
    int* total  = (int*)alloc(CB);
    int* ptr    = (int*)alloc(R + 1);
    uint2* barr = (uint2*)alloc((size_t)E * 2);
    uint2* rec  = (uint2*)alloc((size_t)E * 2);
    uchar_t* ub8 = (uchar_t*)alloc((size_t)U * DIM / 4);
    uchar_t* ib8 = (uchar_t*)alloc((size_t)I * DIM / 4);
    float* u1  = (float*)alloc((size_t)U * DIM);
    float* i1  = (float*)alloc((size_t)I * DIM);
    (void)ws_size;

    size_t n8u = (size_t)U * DIM / 8, n8t = (size_t)(U + I) * DIM / 8;

    // ---- CSR build: ONE cooperative dispatch (count|blkscan|place|finalize fused) ----
    int Es_ = Es, Eui_ = Eui, Eiu_ = Eiu, U_ = U, R_ = R, CB_ = CB;
    void* kargs[] = {
        (void*)&user_emb, (void*)&item_emb, (void*)&ub8, (void*)&ib8,
        (void*)&n8u, (void*)&n8t,
        (void*)&sn_row, (void*)&sn_col, (void*)&ci_row, (void*)&ci_col,
        (void*)&ic_row, (void*)&ic_col,
        (void*)&snii1, (void*)&snii2, (void*)&ciii1, (void*)&ciii2,
        (void*)&icii1, (void*)&icii2, (void*)&low_w, (void*)&low_b,
        (void*)&cnt, (void*)&blkoff, (void*)&total, (void*)&ptr,
        (void*)&barr, (void*)&rec,
        (void*)&Es_, (void*)&Eui_, (void*)&Eiu_, (void*)&U_, (void*)&R_, (void*)&CB_
    };
    hipLaunchCooperativeKernel((void*)build_kernel, dim3(NBLK_C), dim3(NTHR),
                               kargs, 0, stream);

    // ---- layer 1: one row per 8-lane group, 32 rows per 256-thr block ----
    layer1_kernel<<<(U + I + 31) / 32, 256, 0, stream>>>(ub8, ib8, user_emb, item_emb,
        ptr, rec, att1_W, att1_b, att2_w, att2_b, u1, i1, U, I);

    // ---- fused layer2+final: one wave per sample ----
    l2f_kernel<<<(B + 3) / 4, 256, 0, stream>>>(user_emb, item_emb, u1, i1, ptr, rec,
        att1_W, att1_b, att2_w, att2_b, user_idx, item_idx, out, U, B);
}

// Round 13
// 292.111 us; speedup vs baseline: 1.4316x; 1.4316x over previous
//
#include <hip/hip_runtime.h>
#include <math.h>

#define DIM 64
#define NBLK_P 512       // count/place blocks; 2/CU. R9 lesson: never fewer blocks than CUs.
#define NTHR 1024
#define CBSZ 1024        // rows per coarse bucket (R10-verified): write-amp ~1.4x + full occ
#define CBMAX 256        // CB = ceil(R/1024) = 245 <= 256
#define HREP 4           // R13: replicated count histograms (R12 PMC: 900K LDS bank-conflict
#define HPAD (CBMAX + 8) //      cycles -> same-address atomic serialization is the build cost)

// PMC-verified lessons: R5/R8 global atomics & scattered 8B stores = line-granular HBM
// round-trips (atomics stay in LDS); R6 1024-thr layer blocks -> degree-variance tail;
// R9 grids < 256 blocks starve CUs; R12 cooperative launch costs ~130us in graph replay.

typedef unsigned short ushort_t;
typedef unsigned int uint_t;
typedef unsigned char uchar_t;
typedef float v2f __attribute__((ext_vector_type(2)));

__device__ __forceinline__ ushort_t f2bf(float f) {
    uint_t u = __float_as_uint(f);
    return (ushort_t)((u + 0x7fffu + ((u >> 16) & 1u)) >> 16);
}

// ---------------- pass 1: fp8 tables + per-(block, coarse-bucket) counts (x4 vectorized) -----
// R13: 4-way replicated histogram — lane-quartet r=(lane>>4)&3 owns h[r][.]; padded stride
// puts the same bucket in different banks per replica; merge at end (order-independent sums).

__device__ __forceinline__ void count_list(const int* __restrict__ rows, int EL, int base,
                                           int* hrep, size_t gtid, size_t GT) {
    size_t nq = ((size_t)EL + 3) >> 2;
    for (size_t q = gtid; q < nq; q += GT) {
        int e = (int)(q << 2);
        if (e + 4 <= EL) {
            int4 r4 = *(const int4*)(rows + e);
            atomicAdd(&hrep[(base + r4.x) >> 10], 1);
            atomicAdd(&hrep[(base + r4.y) >> 10], 1);
            atomicAdd(&hrep[(base + r4.z) >> 10], 1);
            atomicAdd(&hrep[(base + r4.w) >> 10], 1);
        } else {
            for (int j = e; j < EL; j++) atomicAdd(&hrep[(base + rows[j]) >> 10], 1);
        }
    }
}

__global__ void count_cvt_kernel(const float* __restrict__ u0, const float* __restrict__ i0,
                                 uchar_t* __restrict__ ub, uchar_t* __restrict__ ib,
                                 size_t n8u, size_t n8t,
                                 const int* __restrict__ sn_row, const int* __restrict__ ci_row,
                                 const int* __restrict__ ic_row, int* __restrict__ cnt,
                                 int Es, int Eui, int Eiu, int U, int CB) {
    __shared__ int h[HREP * HPAD];
    int b = blockIdx.x, tid = threadIdx.x;
    size_t gtid = (size_t)b * NTHR + tid;
    const size_t GT = (size_t)NBLK_P * NTHR;

    // fp8 conversion (emb ~N(0,0.01^2) x256 in e4m3 normal range; verified absmax 0.0)
    for (size_t i = gtid; i < n8t; i += GT) {
        const float4* src; uchar_t* dst; size_t di;
        if (i < n8u) { src = (const float4*)u0; dst = ub; di = i; }
        else         { src = (const float4*)i0; dst = ib; di = i - n8u; }
        float4 a = src[2 * di], c = src[2 * di + 1];
        int lo = 0, hi = 0;
        lo = __builtin_amdgcn_cvt_pk_fp8_f32(a.x * 256.0f, a.y * 256.0f, lo, false);
        lo = __builtin_amdgcn_cvt_pk_fp8_f32(a.z * 256.0f, a.w * 256.0f, lo, true);
        hi = __builtin_amdgcn_cvt_pk_fp8_f32(c.x * 256.0f, c.y * 256.0f, hi, false);
        hi = __builtin_amdgcn_cvt_pk_fp8_f32(c.z * 256.0f, c.w * 256.0f, hi, true);
        ((uint2*)dst)[di] = make_uint2((uint_t)lo, (uint_t)hi);
    }

    for (int i = tid; i < HREP * HPAD; i += NTHR) h[i] = 0;
    __syncthreads();
    int* hrep = h + ((tid >> 4) & (HREP - 1)) * HPAD;
    count_list(sn_row, Es, 0, hrep, gtid, GT);
    count_list(ci_row, Eui, U, hrep, gtid, GT);
    count_list(ic_row, Eiu, 2 * U, hrep, gtid, GT);
    __syncthreads();
    if (tid < CB)
        cnt[(size_t)b * CB + tid] = h[tid] + h[HPAD + tid] + h[2 * HPAD + tid] + h[3 * HPAD + tid];
}

// ---------------- pass 2: per-bucket exclusive scan over 512 blocks (CB-parallel) ------------

__global__ void blkscan_kernel(const int* __restrict__ cnt, int* __restrict__ blkoff,
                               int* __restrict__ total, int CB) {
    int c = blockIdx.x;
    int b = threadIdx.x;                  // NBLK_P threads = 8 waves
    int v = cnt[(size_t)b * CB + c];
    int lane = b & 63, wid = b >> 6;
    int inc = v;
    #pragma unroll
    for (int off = 1; off < 64; off <<= 1) {
        int x = __shfl_up(inc, off, 64);
        if (lane >= off) inc += x;
    }
    __shared__ int ws[NBLK_P / 64];
    if (lane == 63) ws[wid] = inc;
    __syncthreads();
    int woff = 0;
    for (int j = 0; j < wid; j++) woff += ws[j];
    blkoff[(size_t)b * CB + c] = inc - v + woff;
    if (b == NBLK_P - 1) total[c] = inc + woff;
}

// ---- inline CB-prefix (replaces the cstart dispatch) ----------------------------------------
// Requires blockDim >= 256; first 4 waves compute exclusive prefix of total[0..CB) into cs.

__device__ __forceinline__ void cb_prefix(const int* __restrict__ total, int CB,
                                          int* cs, int* wsx) {
    int t = threadIdx.x;
    int lane = t & 63, wv = t >> 6;
    int v = 0, inc = 0;
    if (t < 256) {
        v = (t < CB) ? total[t] : 0;
        inc = v;
        #pragma unroll
        for (int off = 1; off < 64; off <<= 1) {
            int x = __shfl_up(inc, off, 64);
            if (lane >= off) inc += x;
        }
        if (lane == 63) wsx[wv] = inc;
    }
    __syncthreads();
    if (t < 256) {
        int woff = 0;
        for (int j = 0; j < wv; j++) woff += wsx[j];
        if (t < CB) cs[t] = inc - v + woff;
        if (t == CB - 1) cs[CB] = inc + woff;     // = E
    }
    __syncthreads();
}

// ---------------- pass 3: place 8B records {rin10<<22|col, bf16(t2)<<16|bf16(t1)} ------------
// t = exp(exp(sigmoid(raw*w+b))) in (2.72,15.2): softmax w/o max-sub is safe; LDS atomics only.
// x4-vectorized edge reads with per-list hoisted weights (quad mapping must match count_list
// exactly for blkoff consistency). cur stays single-copy (unique positions). col < 2^22.

__device__ __forceinline__ void place_edge(int v, int c, float r1, float r2,
                                           float w1, float b1, float w2, float b2,
                                           int* cur, uint2* __restrict__ barr) {
    float t1 = expf(expf(1.0f / (1.0f + expf(-(r1 * w1 + b1)))));
    float t2 = expf(expf(1.0f / (1.0f + expf(-(r2 * w2 + b2)))));
    uint_t packed = (uint_t)f2bf(t1) | ((uint_t)f2bf(t2) << 16);
    int pos = atomicAdd(&cur[v >> 10], 1);
    barr[pos] = make_uint2(((uint_t)(v & 1023) << 22) | (uint_t)c, packed);
}

__device__ __forceinline__ void place_list(const int* __restrict__ rows, const int* __restrict__ cols,
                                           const float* __restrict__ x1, const float* __restrict__ x2,
                                           int EL, int base, float w1, float b1, float w2, float b2,
                                           int* cur, uint2* __restrict__ barr,
                                           size_t gtid, size_t GT) {
    size_t nq = ((size_t)EL + 3) >> 2;
    for (size_t q = gtid; q < nq; q += GT) {
        int e = (int)(q << 2);
        if (e + 4 <= EL) {
            int4 r4 = *(const int4*)(rows + e);
            int4 c4 = *(const int4*)(cols + e);
            float4 a4 = *(const float4*)(x1 + e);
            float4 b4 = *(const float4*)(x2 + e);
            place_edge(base + r4.x, c4.x, a4.x, b4.x, w1, b1, w2, b2, cur, barr);
            place_edge(base + r4.y, c4.y, a4.y, b4.y, w1, b1, w2, b2, cur, barr);
            place_edge(base + r4.z, c4.z, a4.z, b4.z, w1, b1, w2, b2, cur, barr);
            place_edge(base + r4.w, c4.w, a4.w, b4.w, w1, b1, w2, b2, cur, barr);
        } else {
            for (int j = e; j < EL; j++)
                place_edge(base + rows[j], cols[j], x1[j], x2[j], w1, b1, w2, b2, cur, barr);
        }
    }
}

__global__ void place_kernel(const int* __restrict__ sn_row, const int* __restrict__ sn_col,
                             const int* __restrict__ ci_row, const int* __restrict__ ci_col,
                             const int* __restrict__ ic_row, const int* __restrict__ ic_col,
                             const float* __restrict__ snii1, const float* __restrict__ snii2,
                             const float* __restrict__ ciii1, const float* __restrict__ ciii2,
                             const float* __restrict__ icii1, const float* __restrict__ icii2,
                             const float* __restrict__ lw, const float* __restrict__ lb,
                             const int* __restrict__ total, const int* __restrict__ blkoff,
                             uint2* __restrict__ barr,
                             int Es, int Eui, int Eiu, int U, int CB) {
    __shared__ int cs[CBMAX + 1];
    __shared__ int wsx[4];
    __shared__ int cur[CBMAX];
    int b = blockIdx.x;
    cb_prefix(total, CB, cs, wsx);
    if (threadIdx.x < CB)
        cur[threadIdx.x] = cs[threadIdx.x] + blkoff[(size_t)b * CB + threadIdx.x];
    __syncthreads();
    size_t gtid = (size_t)b * NTHR + threadIdx.x;
    const size_t GT = (size_t)NBLK_P * NTHR;
    place_list(sn_row, sn_col, snii1, snii2, Es, 0,      lw[0], lb[0], lw[1], lb[1], cur, barr, gtid, GT);
    place_list(ci_row, ci_col, ciii1, ciii2, Eui, U,     lw[2], lb[2], lw[3], lb[3], cur, barr, gtid, GT);
    place_list(ic_row, ic_col, icii1, icii2, Eiu, 2 * U, lw[4], lb[4], lw[5], lb[5], cur, barr, gtid, GT);
}

// ---------------- pass 4: one block per coarse bucket: 1024-row histo + scan + scatter -------
// Single-writer dense rec region per block -> full-line writes; all atomics in LDS.

__global__ void finalize_kernel(const uint2* __restrict__ barr, const int* __restrict__ total,
                                int* __restrict__ ptr, uint2* __restrict__ rec,
                                int R, int CB) {
    __shared__ int cs[CBMAX + 1];
    __shared__ int wsx[4];
    __shared__ int hist[CBSZ];
    __shared__ int cur2[CBSZ];
    __shared__ int wss[NTHR / 64];
    int c = blockIdx.x, tid = threadIdx.x;
    cb_prefix(total, CB, cs, wsx);
    int s0 = cs[c], s1 = cs[c + 1];
    hist[tid] = 0;
    __syncthreads();
    for (int e = s0 + tid; e < s1; e += NTHR)
        atomicAdd(&hist[barr[e].x >> 22], 1);
    __syncthreads();
    int v = hist[tid];
    int lane = tid & 63, wid = tid >> 6;
    int inc = v;
    #pragma unroll
    for (int off = 1; off < 64; off <<= 1) {
        int x = __shfl_up(inc, off, 64);
        if (lane >= off) inc += x;
    }
    if (lane == 63) wss[wid] = inc;
    __syncthreads();
    int woff = 0;
    for (int j = 0; j < wid; j++) woff += wss[j];
    int p0 = s0 + inc - v + woff;                 // CSR start for row c*1024+tid
    int r = c * CBSZ + tid;
    if (r < R) ptr[r] = p0;
    cur2[tid] = p0;
    if (c == CB - 1 && tid == 0) ptr[R] = cs[CB];
    __syncthreads();
    for (int e = s0 + tid; e < s1; e += NTHR) {
        uint2 q = barr[e];
        int rin = (int)(q.x >> 22);
        int pos = atomicAdd(&cur2[rin], 1);
        rec[pos] = make_uint2(q.x & 0x3FFFFFu, q.y);
    }
}

// ---------------- layer kernels ----------------

__device__ __forceinline__ float att_scalar(float dot, float b1, float w2, float b2, float addc) {
    float h = tanhf(dot + b1);
    float z = h * w2 + b2;
    float lr = z > 0.0f ? z : 0.2f * z;   // leaky_relu alpha=0.2
    return expf(lr) + addc;
}

// packed fp8 -> float2 FMA: 4 cvt + 4 packed FMAs per 8 dims (v_pk_fma_f32)
__device__ __forceinline__ void fp8_fma8v(v2f acc[4], uint2 v, float a) {
    v2f av = {a, a};
    acc[0] += av * __builtin_amdgcn_cvt_pk_f32_fp8((int)v.x, false);
    acc[1] += av * __builtin_amdgcn_cvt_pk_f32_fp8((int)v.x, true);
    acc[2] += av * __builtin_amdgcn_cvt_pk_f32_fp8((int)v.y, false);
    acc[3] += av * __builtin_amdgcn_cvt_pk_f32_fp8((int)v.y, true);
}

__device__ __forceinline__ float dot8_lanes(float d) {
    #pragma unroll
    for (int off = 1; off < 8; off <<= 1) d += __shfl_xor(d, off, 64);
    return d;
}

// BRANCH-FREE batched CSR walk (R14). 8 lanes load 8 different records (coalesced),
// prefetch next batch via clamped load + cndmask. Padded records are (0,0): cx=0 is a
// valid row-0 gather and a=0 makes the FMA a no-op -> no divergent branches, 8
// independent gathers clustered per batch.
__device__ __forceinline__ void agg_row8(const uint2* __restrict__ rec, const uchar_t* __restrict__ tab,
                                         int e0, int e1, int l8, int lanebase,
                                         v2f acc[4], float& s) {
    if (e0 >= e1) return;
    int last = e1 - 1;
    int idx0 = e0 + l8;
    uint2 t0 = rec[min(idx0, last)];
    uint2 q;
    q.x = (idx0 <= last) ? t0.x : 0u;
    q.y = (idx0 <= last) ? t0.y : 0u;
    for (int base = e0; base < e1; base += 8) {
        int nidx = base + 8 + l8;
        uint2 tn = rec[min(nidx, last)];          // unconditional clamped prefetch
        uint2 qn;
        qn.x = (nidx <= last) ? tn.x : 0u;
        qn.y = (nidx <= last) ? tn.y : 0u;
        s += __uint_as_float(q.y << 16);          // per-lane partial of bf16 t1 (0 if padded)
        #pragma unroll
        for (int j = 0; j < 8; j++) {
            uint_t cx = __shfl(q.x, lanebase + j, 64);
            uint_t wy = __shfl(q.y, lanebase + j, 64);
            float a = __uint_as_float(wy << 16);
            uint2 v = ((const uint2*)(tab + (size_t)cx * DIM))[l8];
            fp8_fma8v(acc, v, a);
        }
        q = qn;
    }
}

// one row per 8-lane group; 256-thr blocks (R6 lesson: 1024-thr blocks -> 41% occupancy).
__global__ void layer1_kernel(const uchar_t* __restrict__ ub8, const uchar_t* __restrict__ ib8,
                              const float* __restrict__ u0, const float* __restrict__ i0,
                              const int* __restrict__ ptr, const uint2* __restrict__ rec,
                              const float* __restrict__ W1, const float* __restrict__ b1v,
                              const float* __restrict__ w2v, const float* __restrict__ b2v,
                              float* __restrict__ u1, float* __restrict__ i1, int U, int I) {
    int gid = blockIdx.x * (blockDim.x >> 3) + (threadIdx.x >> 3);
    int lane = threadIdx.x & 63;
    int l8 = lane & 7;
    int lanebase = lane & 56;
    if (gid >= U + I) return;
    bool is_user = gid < U;
    int r = is_user ? gid : gid - U;

    v2f A[4]  = {{0.f, 0.f}, {0.f, 0.f}, {0.f, 0.f}, {0.f, 0.f}};
    v2f Bv[4] = {{0.f, 0.f}, {0.f, 0.f}, {0.f, 0.f}, {0.f, 0.f}};
    float s_a = 0.f, s_b = 0.f;

    if (is_user) {
        agg_row8(rec, ib8, ptr[U + r], ptr[U + r + 1], l8, lanebase, A, s_a);   // u_from_i (ci)
        agg_row8(rec, ub8, ptr[r], ptr[r + 1], l8, lanebase, Bv, s_b);          // u_from_u (sn)
    } else {
        agg_row8(rec, ub8, ptr[2 * U + r], ptr[2 * U + r + 1], l8, lanebase, A, s_a);  // i_from_u (ic)
    }
    s_a = dot8_lanes(s_a);
    s_b = dot8_lanes(s_b);

    float ka = (1.0f / (s_a + 1e-12f)) * 0.00390625f;   // softmax denom * fp8 scale
    float kb = (1.0f / (s_b + 1e-12f)) * 0.00390625f;
    float ac[8], bc[8];
    #pragma unroll
    for (int j = 0; j < 4; j++) {
        ac[2 * j] = A[j][0] * ka;  ac[2 * j + 1] = A[j][1] * ka;
        bc[2 * j] = Bv[j][0] * kb; bc[2 * j + 1] = Bv[j][1] * kb;
    }

    const float* selfp = (is_user ? u0 : i0) + (size_t)r * DIM + 8 * l8;
    float4 s0 = *(const float4*)selfp;
    float4 s1 = *(const float4*)(selfp + 4);
    float sf[8] = {s0.x, s0.y, s0.z, s0.w, s1.x, s1.y, s1.z, s1.w};
    int k = is_user ? 0 : 4;
    const float* Wa = W1 + k * 2 * DIM;
    const float* Wb = Wa + 2 * DIM;
    float d1 = 0.f, d2 = 0.f;
    #pragma unroll
    for (int j = 0; j < 8; j++) {
        float wa0 = Wa[8 * l8 + j], wa1 = Wa[DIM + 8 * l8 + j];
        float wb0 = Wb[8 * l8 + j], wb1 = Wb[DIM + 8 * l8 + j];
        if (is_user) {
            d1 += sf[j] * wa0 + ac[j] * wa1;
            d2 += sf[j] * wb0 + bc[j] * wb1;
        } else {
            d1 += sf[j] * (wa0 + wa1);                 // concat([it, it])
            d2 += sf[j] * wb0 + ac[j] * wb1;
        }
    }
    d1 = dot8_lanes(d1);
    d2 = dot8_lanes(d2);

    float out8[8];
    float* op;
    if (is_user) {
        float a_int = att_scalar(d1, b1v[0], w2v[0], b2v[0], 0.7f);
        float a_soc = att_scalar(d2, b1v[1], w2v[1], b2v[1], 0.3f);
        float sg = a_int + a_soc;
        float wi = a_int / sg, ws = a_soc / sg;
        #pragma unroll
        for (int j = 0; j < 8; j++)
            out8[j] = 0.5f * sf[j] + 0.5f * (wi * ac[j] + ws * bc[j]);
        op = u1 + (size_t)r * DIM + 8 * l8;
    } else {
        float a_self = att_scalar(d1, b1v[4], w2v[4], b2v[4], 1.0f);
        float a_cust = att_scalar(d2, b1v[5], w2v[5], b2v[5], 1.0f);
        float sg = a_self + a_cust;
        float wi = a_self / sg, ws = a_cust / sg;
        #pragma unroll
        for (int j = 0; j < 8; j++)
            out8[j] = wi * sf[j] + ws * ac[j];
        op = i1 + (size_t)r * DIM + 8 * l8;
    }
    *(float4*)op = make_float4(out8[0], out8[1], out8[2], out8[3]);
    *(float4*)(op + 4) = make_float4(out8[4], out8[5], out8[6], out8[7]);
}

// ---------------- fused layer2+final — one wave per sample; u2/i2 never hit global ----------

__global__ void l2f_kernel(const float* __restrict__ u0, const float* __restrict__ i0,
                           const float* __restrict__ u1, const float* __restrict__ i1,
                           const int* __restrict__ ptr, const uint2* __restrict__ rec,
                           const float* __restrict__ W1, const float* __restrict__ b1v,
                           const float* __restrict__ w2v, const float* __restrict__ b2v,
                           const int* __restrict__ uidx, const int* __restrict__ iidx,
                           float* __restrict__ out, int U, int B) {
    int wid = blockIdx.x * (blockDim.x >> 6) + (threadIdx.x >> 6);
    int lane = threadIdx.x & 63;
    if (wid >= B) return;
    int g = lane >> 3, l8 = lane & 7;
    int ru = uidx[wid], ri = iidx[wid];

    // ---- user phase: u2 row of ru ----
    float aa[8] = {0, 0, 0, 0, 0, 0, 0, 0};
    float ab[8] = {0, 0, 0, 0, 0, 0, 0, 0};
    float s_a = 0.f, s_b = 0.f;
    int e0 = ptr[U + ru], e1 = ptr[U + ru + 1];
    for (int e = e0 + g; e < e1; e += 8) {
        uint2 q = rec[e];
        float a = __uint_as_float(q.y & 0xffff0000u);  // bf16 t2
        s_a += a;
        const float4* rp = (const float4*)(i1 + (size_t)q.x * DIM);
        float4 v0 = rp[2 * l8], v1 = rp[2 * l8 + 1];
        aa[0] = fmaf(a, v0.x, aa[0]); aa[1] = fmaf(a, v0.y, aa[1]);
        aa[2] = fmaf(a, v0.z, aa[2]); aa[3] = fmaf(a, v0.w, aa[3]);
        aa[4] = fmaf(a, v1.x, aa[4]); aa[5] = fmaf(a, v1.y, aa[5]);
        aa[6] = fmaf(a, v1.z, aa[6]); aa[7] = fmaf(a, v1.w, aa[7]);
    }
    e0 = ptr[ru]; e1 = ptr[ru + 1];
    for (int e = e0 + g; e < e1; e += 8) {
        uint2 q = rec[e];
        float a = __uint_as_float(q.y & 0xffff0000u);
        s_b += a;
        const float4* rp = (const float4*)(u1 + (size_t)q.x * DIM);
        float4 v0 = rp[2 * l8], v1 = rp[2 * l8 + 1];
        ab[0] = fmaf(a, v0.x, ab[0]); ab[1] = fmaf(a, v0.y, ab[1]);
        ab[2] = fmaf(a, v0.z, ab[2]); ab[3] = fmaf(a, v0.w, ab[3]);
        ab[4] = fmaf(a, v1.x, ab[4]); ab[5] = fmaf(a, v1.y, ab[5]);
        ab[6] = fmaf(a, v1.z, ab[6]); ab[7] = fmaf(a, v1.w, ab[7]);
    }
    #pragma unroll
    for (int off = 8; off < 64; off <<= 1) {
        s_a += __shfl_xor(s_a, off, 64);
        s_b += __shfl_xor(s_b, off, 64);
        #pragma unroll
        for (int j = 0; j < 8; j++) {
            aa[j] += __shfl_xor(aa[j], off, 64);
            ab[j] += __shfl_xor(ab[j], off, 64);
        }
    }
    float ka = 1.0f / (s_a + 1e-12f);
    float kb = 1.0f / (s_b + 1e-12f);
    #pragma unroll
    for (int j = 0; j < 8; j++) { aa[j] *= ka; ab[j] *= kb; }

    const float* sup = u1 + (size_t)ru * DIM + 8 * l8;
    float4 su0 = *(const float4*)sup;
    float4 su1 = *(const float4*)(sup + 4);
    float sfu[8] = {su0.x, su0.y, su0.z, su0.w, su1.x, su1.y, su1.z, su1.w};
    {
        const float* Wa = W1 + 2 * 2 * DIM;            // k=2
        const float* Wb = Wa + 2 * DIM;
        float d1 = 0.f, d2 = 0.f;
        #pragma unroll
        for (int j = 0; j < 8; j++) {
            d1 += sfu[j] * Wa[8 * l8 + j] + aa[j] * Wa[DIM + 8 * l8 + j];
            d2 += sfu[j] * Wb[8 * l8 + j] + ab[j] * Wb[DIM + 8 * l8 + j];
        }
        d1 = dot8_lanes(d1);
        d2 = dot8_lanes(d2);
        float a_int = att_scalar(d1, b1v[2], w2v[2], b2v[2], 0.7f);
        float a_soc = att_scalar(d2, b1v[3], w2v[3], b2v[3], 0.3f);
        float sg = a_int + a_soc;
        float wi = a_int / sg, ws = a_soc / sg;
        #pragma unroll
        for (int j = 0; j < 8; j++)
            aa[j] = 0.5f * sfu[j] + 0.5f * (wi * aa[j] + ws * ab[j]);   // aa := u2 dims
    }

    // ---- item phase: i2 row of ri ----
    float ac[8] = {0, 0, 0, 0, 0, 0, 0, 0};
    float s_c = 0.f;
    e0 = ptr[2 * U + ri]; e1 = ptr[2 * U + ri + 1];
    for (int e = e0 + g; e < e1; e += 8) {
        uint2 q = rec[e];
        float a = __uint_as_float(q.y & 0xffff0000u);
        s_c += a;
        const float4* rp = (const float4*)(u1 + (size_t)q.x * DIM);
        float4 v0 = rp[2 * l8], v1 = rp[2 * l8 + 1];
        ac[0] = fmaf(a, v0.x, ac[0]); ac[1] = fmaf(a, v0.y, ac[1]);
        ac[2] = fmaf(a, v0.z, ac[2]); ac[3] = fmaf(a, v0.w, ac[3]);
        ac[4] = fmaf(a, v1.x, ac[4]); ac[5] = fmaf(a, v1.y, ac[5]);
        ac[6] = fmaf(a, v1.z, ac[6]); ac[7] = fmaf(a, v1.w, ac[7]);
    }
    #pragma unroll
    for (int off = 8; off < 64; off <<= 1) {
        s_c += __shfl_xor(s_c, off, 64);
        #pragma unroll
        for (int j = 0; j < 8; j++) ac[j] += __shfl_xor(ac[j], off, 64);
    }
    float kc = 1.0f / (s_c + 1e-12f);
    #pragma unroll
    for (int j = 0; j < 8; j++) ac[j] *= kc;

    const float* sip = i1 + (size_t)ri * DIM + 8 * l8;
    float4 si0 = *(const float4*)sip;
    float4 si1 = *(const float4*)(sip + 4);
    float sfi[8] = {si0.x, si0.y, si0.z, si0.w, si1.x, si1.y, si1.z, si1.w};
    {
        const float* Wa = W1 + 6 * 2 * DIM;            // k=6
        const float* Wb = Wa + 2 * DIM;
        float d1 = 0.f, d2 = 0.f;
        #pragma unroll
        for (int j = 0; j < 8; j++) {
            d1 += sfi[j] * (Wa[8 * l8 + j] + Wa[DIM + 8 * l8 + j]);   // concat([it, it])
            d2 += sfi[j] * Wb[8 * l8 + j] + ac[j] * Wb[DIM + 8 * l8 + j];
        }
        d1 = dot8_lanes(d1);
        d2 = dot8_lanes(d2);
        float a_self = att_scalar(d1, b1v[6], w2v[6], b2v[6], 1.0f);
        float a_cust = att_scalar(d2, b1v[7], w2v[7], b2v[7], 1.0f);
        float sg = a_self + a_cust;
        float wi = a_self / sg, ws = a_cust / sg;
        #pragma unroll
        for (int j = 0; j < 8; j++)
            ac[j] = wi * sfi[j] + ws * ac[j];           // ac := i2 dims
    }

    // ---- final: sigmoid(u0.i0 + u1.i1 + u2.i2) ----
    float p = 0.f;
    #pragma unroll
    for (int j = 0; j < 8; j++) p += aa[j] * ac[j];
    p = dot8_lanes(p);                                  // u2.i2 (same in all lanes)
    float qd = u0[(size_t)ru * DIM + lane] * i0[(size_t)ri * DIM + lane]
             + u1[(size_t)ru * DIM + lane] * i1[(size_t)ri * DIM + lane];
    #pragma unroll
    for (int off = 32; off > 0; off >>= 1) qd += __shfl_xor(qd, off, 64);
    if (lane == 0) out[wid] = 1.0f / (1.0f + expf(-(p + qd)));
}

// ---------------- launch ----------------

extern "C" void kernel_launch(void* const* d_in, const int* in_sizes, int n_in,
                              void* d_out, int out_size, void* d_ws, size_t ws_size,
                              hipStream_t stream) {
    const float* user_emb = (const float*)d_in[0];
    const float* item_emb = (const float*)d_in[1];
    const float* snii1 = (const float*)d_in[2];
    const float* snii2 = (const float*)d_in[3];
    const float* ciii1 = (const float*)d_in[4];
    const float* ciii2 = (const float*)d_in[5];
    const float* icii1 = (const float*)d_in[6];
    const float* icii2 = (const float*)d_in[7];
    const float* low_w = (const float*)d_in[8];
    const float* low_b = (const float*)d_in[9];
    const float* att1_W = (const float*)d_in[10];
    const float* att1_b = (const float*)d_in[11];
    const float* att2_w = (const float*)d_in[12];
    const float* att2_b = (const float*)d_in[13];
    const int* sn_row = (const int*)d_in[14];
    const int* sn_col = (const int*)d_in[15];
    const int* ci_row = (const int*)d_in[16];
    const int* ci_col = (const int*)d_in[17];
    const int* ic_row = (const int*)d_in[18];
    const int* ic_col = (const int*)d_in[19];
    const int* user_idx = (const int*)d_in[20];
    const int* item_idx = (const int*)d_in[21];
    float* out = (float*)d_out;

    const int Es  = in_sizes[2];
    const int Eui = in_sizes[4];
    const int Eiu = in_sizes[6];
    const int U = in_sizes[0] / DIM;
    const int I = in_sizes[1] / DIM;
    const int B = in_sizes[20];
    const int R = 2 * U + I;                // virtual rows: [0,U)=sn, [U,2U)=ci, [2U,2U+I)=ic
    const int CB = (R + CBSZ - 1) / CBSZ;   // 245 coarse buckets <= CBMAX
    const int E = Es + Eui + Eiu;
    (void)E;

    // ---- workspace carve (4-byte units, 16B-aligned) ----
    char* wsb = (char*)d_ws;
    size_t off = 0;
    auto alloc = [&](size_t n_units) {
        off = (off + 3) & ~(size_t)3;
        void* p = wsb + off * 4; off += n_units; return p;
    };

    int* cnt    = (int*)alloc((size_t)NBLK_P * CB);
    int* blkoff = (int*)alloc((size_t)NBLK_P * CB);
    int* total  = (int*)alloc(CB);
    int* ptr    = (int*)alloc(R + 1);
    uint2* barr = (uint2*)alloc((size_t)E * 2);
    uint2* rec  = (uint2*)alloc((size_t)E * 2);
    uchar_t* ub8 = (uchar_t*)alloc((size_t)U * DIM / 4);
    uchar_t* ib8 = (uchar_t*)alloc((size_t)I * DIM / 4);
    float* u1  = (float*)alloc((size_t)U * DIM);
    float* i1  = (float*)alloc((size_t)I * DIM);
    (void)ws_size;

    size_t n8u = (size_t)U * DIM / 8, n8t = (size_t)(U + I) * DIM / 8;

    // ---- CSR build (4 dispatches): cvt+count | blkscan | place | finalize ----
    count_cvt_kernel<<<NBLK_P, NTHR, 0, stream>>>(user_emb, item_emb, ub8, ib8, n8u, n8t,
                                                  sn_row, ci_row, ic_row, cnt,
                                                  Es, Eui, Eiu, U, CB);
    blkscan_kernel<<<CB, NBLK_P, 0, stream>>>(cnt, blkoff, total, CB);
    place_kernel<<<NBLK_P, NTHR, 0, stream>>>(sn_row, sn_col, ci_row, ci_col, ic_row, ic_col,
                                              snii1, snii2, ciii1, ciii2, icii1, icii2,
                                              low_w, low_b, total, blkoff, barr,
                                              Es, Eui, Eiu, U, CB);
    finalize_kernel<<<CB, NTHR, 0, stream>>>(barr, total, ptr, rec, R, CB);

    // ---- layer 1: one row per 8-lane group, 32 rows per 256-thr block ----
    layer1_kernel<<<(U + I + 31) / 32, 256, 0, stream>>>(ub8, ib8, user_emb, item_emb,
        ptr, rec, att1_W, att1_b, att2_w, att2_b, u1, i1, U, I);

    // ---- fused layer2+final: one wave per sample ----
    l2f_kernel<<<(B + 3) / 4, 256, 0, stream>>>(user_emb, item_emb, u1, i1, ptr, rec,
        att1_W, att1_b, att2_w, att2_b, user_idx, item_idx, out, U, B);
}